// Round 1
// baseline (2081.442 us; speedup 1.0000x reference)
//
#include <hip/hip_runtime.h>
#include <hip/hip_bf16.h>
#include <math.h>

#define HIDDEN 1024
#define HEADS 16
#define DK 64
#define BATCH 2
#define SLEN 2048

// ---------------------------------------------------------------------------
// GEMM: Y = A @ W + bias.  A: [M=4096][1024], W: [1024][1024], bias: [1024]
// head_split=1 -> Y[((b*HEADS + h)*SLEN + s)*64 + d]  (h = n>>6, d = n&63)
// head_split=0 -> Y[m][n] flat
// Tile 64x64, 256 threads, 4x4 per thread, K-step 16.
// LDS stride 68 floats: 16B-aligned rows (68*4=272=17*16), conflict-free reads.
// ---------------------------------------------------------------------------
__global__ __launch_bounds__(256) void gemm_bias_kernel(
    const float* __restrict__ A, const float* __restrict__ W,
    const float* __restrict__ bias, float* __restrict__ Y, int head_split)
{
  __shared__ float As[16][68];  // As[k][m] (transposed A tile)
  __shared__ float Bs[16][68];  // Bs[k][n]

  const int tid = threadIdx.x;
  const int bm = blockIdx.x >> 4;
  const int bn = blockIdx.x & 15;
  const int m0 = bm * 64, n0 = bn * 64;
  const int tm = tid & 15;   // row group 0..15
  const int tn = tid >> 4;   // col group 0..15

  const int arow = tid >> 2, acol = (tid & 3) << 2;   // A tile load coords
  const int brow = tid >> 4, bcol = (tid & 15) << 2;  // B tile load coords

  float acc[4][4];
#pragma unroll
  for (int i = 0; i < 4; ++i)
#pragma unroll
    for (int j = 0; j < 4; ++j) acc[i][j] = 0.f;

  for (int k0 = 0; k0 < HIDDEN; k0 += 16) {
    float4 a = *(const float4*)(A + (size_t)(m0 + arow) * HIDDEN + k0 + acol);
    As[acol + 0][arow] = a.x;
    As[acol + 1][arow] = a.y;
    As[acol + 2][arow] = a.z;
    As[acol + 3][arow] = a.w;
    *(float4*)&Bs[brow][bcol] =
        *(const float4*)(W + (size_t)(k0 + brow) * HIDDEN + n0 + bcol);
    __syncthreads();

#pragma unroll
    for (int kk = 0; kk < 16; ++kk) {
      float4 av = *(const float4*)&As[kk][tm * 4];
      float4 bv = *(const float4*)&Bs[kk][tn * 4];
      float ar[4] = {av.x, av.y, av.z, av.w};
      float br[4] = {bv.x, bv.y, bv.z, bv.w};
#pragma unroll
      for (int i = 0; i < 4; ++i)
#pragma unroll
        for (int j = 0; j < 4; ++j) acc[i][j] += ar[i] * br[j];
    }
    __syncthreads();
  }

  const int n = n0 + tn * 4;
  float b0 = bias[n + 0], b1 = bias[n + 1], b2 = bias[n + 2], b3 = bias[n + 3];
#pragma unroll
  for (int i = 0; i < 4; ++i) {
    int m = m0 + tm * 4 + i;
    float4 o;
    o.x = acc[i][0] + b0;
    o.y = acc[i][1] + b1;
    o.z = acc[i][2] + b2;
    o.w = acc[i][3] + b3;
    if (head_split) {
      int b = m >> 11, s = m & (SLEN - 1), h = n >> 6, d = n & 63;
      *(float4*)(Y + (((size_t)(b * HEADS + h) * SLEN + s) << 6) + d) = o;
    } else {
      *(float4*)(Y + (size_t)m * HIDDEN + n) = o;
    }
  }
}

// ---------------------------------------------------------------------------
// Flash attention (fp32). One block per (b, h, 64-row q tile).
// 256 threads: 4 threads per q-row; thread j of a quad owns k = kk*4 + j.
// Q row and O accumulator live in registers (all indices static after unroll).
// Online softmax; all-masked rows produce 0 (matches nan_to_num).
// ---------------------------------------------------------------------------
__global__ __launch_bounds__(256, 1) void flash_attn_kernel(
    const float* __restrict__ Qh, const float* __restrict__ Kh,
    const float* __restrict__ Vh, const int* __restrict__ mask,
    float* __restrict__ X)
{
  __shared__ float Ks[64][68];
  __shared__ float Vs[64][68];

  const int tid = threadIdx.x;
  const int qt = blockIdx.x & 31;  // S/64 = 32 q tiles
  const int bh = blockIdx.x >> 5;  // b*HEADS + h
  const int b = bh >> 4;
  const int h = bh & 15;
  const int q0 = qt * 64;
  const int row = tid >> 2;  // 0..63 q-row within tile
  const int j = tid & 3;     // k-column group within quad

  // Q row -> registers
  const float* Qrow = Qh + ((size_t)bh * SLEN + q0 + row) * DK;
  float q[DK];
#pragma unroll
  for (int c = 0; c < 16; ++c) {
    float4 v = *(const float4*)(Qrow + c * 4);
    q[c * 4 + 0] = v.x; q[c * 4 + 1] = v.y;
    q[c * 4 + 2] = v.z; q[c * 4 + 3] = v.w;
  }

  float O[DK];
#pragma unroll
  for (int d = 0; d < DK; ++d) O[d] = 0.f;
  float m_run = -INFINITY, l_run = 0.f;

  const float* Kbase = Kh + (size_t)bh * SLEN * DK;
  const float* Vbase = Vh + (size_t)bh * SLEN * DK;
  const int* mrow = mask + ((size_t)b * SLEN + q0 + row) * SLEN;

  for (int k0 = 0; k0 < SLEN; k0 += 64) {
    // stage K,V tile (64x64) into LDS; 4 float4 pairs per thread
#pragma unroll
    for (int i = 0; i < 4; ++i) {
      int li = tid + i * 256;  // 0..1023 float4 chunks
      int kr = li >> 4;
      int c = (li & 15) << 2;
      *(float4*)&Ks[kr][c] = *(const float4*)(Kbase + ((size_t)(k0 + kr) << 6) + c);
      *(float4*)&Vs[kr][c] = *(const float4*)(Vbase + ((size_t)(k0 + kr) << 6) + c);
    }
    __syncthreads();

    // scores for this thread's 16 k's: k = kk*4 + j
    float s[16];
#pragma unroll
    for (int kk = 0; kk < 16; ++kk) {
      int kr = kk * 4 + j;
      float acc = 0.f;
#pragma unroll
      for (int c = 0; c < 16; ++c) {
        float4 kv = *(const float4*)&Ks[kr][c * 4];
        acc += q[c * 4 + 0] * kv.x + q[c * 4 + 1] * kv.y +
               q[c * 4 + 2] * kv.z + q[c * 4 + 3] * kv.w;
      }
      s[kk] = acc * 0.125f;  // 1/sqrt(64)
    }
    // mask
#pragma unroll
    for (int kk = 0; kk < 16; ++kk) {
      if (mrow[k0 + kk * 4 + j] == 0) s[kk] = -INFINITY;
    }
    // tile max across 16 local + quad lanes
    float tmax = s[0];
#pragma unroll
    for (int kk = 1; kk < 16; ++kk) tmax = fmaxf(tmax, s[kk]);
    tmax = fmaxf(tmax, __shfl_xor(tmax, 1));
    tmax = fmaxf(tmax, __shfl_xor(tmax, 2));
    float mnew = fmaxf(m_run, tmax);

    if (mnew != -INFINITY) {  // skip tiles while everything so far is masked
      float scale = (m_run == -INFINITY) ? 0.f : __expf(m_run - mnew);
      l_run *= scale;
#pragma unroll
      for (int d = 0; d < DK; ++d) O[d] *= scale;

      float p[16];
      float lsum = 0.f;
#pragma unroll
      for (int kk = 0; kk < 16; ++kk) {
        p[kk] = __expf(s[kk] - mnew);  // exp(-inf - finite) = 0
        lsum += p[kk];
      }
      l_run += lsum;

#pragma unroll
      for (int kk = 0; kk < 16; ++kk) {
        float pk = p[kk];
        int kr = kk * 4 + j;
#pragma unroll
        for (int c = 0; c < 16; ++c) {
          float4 vv = *(const float4*)&Vs[kr][c * 4];
          O[c * 4 + 0] += pk * vv.x;
          O[c * 4 + 1] += pk * vv.y;
          O[c * 4 + 2] += pk * vv.z;
          O[c * 4 + 3] += pk * vv.w;
        }
      }
      m_run = mnew;
    }
    __syncthreads();
  }

  // combine the 4 quad lanes
  l_run += __shfl_xor(l_run, 1);
  l_run += __shfl_xor(l_run, 2);
#pragma unroll
  for (int d = 0; d < DK; ++d) {
    O[d] += __shfl_xor(O[d], 1);
    O[d] += __shfl_xor(O[d], 2);
  }
  float inv = (l_run > 0.f) ? 1.f / l_run : 0.f;

  // thread j writes d = j*16 .. j*16+15 of its row, [B][S][HIDDEN] layout
  float* xout = X + ((size_t)b * SLEN + q0 + row) * HIDDEN + h * DK;
#pragma unroll
  for (int c = 0; c < 4; ++c) {
    int d = j * 16 + c * 4;
    float4 o;
    o.x = O[d + 0] * inv; o.y = O[d + 1] * inv;
    o.z = O[d + 2] * inv; o.w = O[d + 3] * inv;
    *(float4*)(xout + d) = o;
  }
}

// ---------------------------------------------------------------------------
extern "C" void kernel_launch(void* const* d_in, const int* in_sizes, int n_in,
                              void* d_out, int out_size, void* d_ws, size_t ws_size,
                              hipStream_t stream) {
  const float* q   = (const float*)d_in[0];
  const float* k   = (const float*)d_in[1];
  const float* v   = (const float*)d_in[2];
  const int*  mask = (const int*)d_in[3];
  const float* Wq  = (const float*)d_in[4];
  const float* bq  = (const float*)d_in[5];
  const float* Wk  = (const float*)d_in[6];
  const float* bk  = (const float*)d_in[7];
  const float* Wv  = (const float*)d_in[8];
  const float* bv  = (const float*)d_in[9];
  const float* Wo  = (const float*)d_in[10];
  const float* bo  = (const float*)d_in[11];
  float* out = (float*)d_out;

  const size_t HSZ = (size_t)BATCH * SLEN * HIDDEN;  // 4,194,304 floats
  float* ws = (float*)d_ws;
  float* Qh = ws;            // [B*H][S][64]
  float* Kh = ws + HSZ;
  float* Vh = ws + 2 * HSZ;
  float* Xa = ws + 3 * HSZ;  // [B][S][HIDDEN]

  const int gemm_grid = (BATCH * SLEN / 64) * (HIDDEN / 64);  // 1024

  gemm_bias_kernel<<<gemm_grid, 256, 0, stream>>>(q, Wq, bq, Qh, 1);
  gemm_bias_kernel<<<gemm_grid, 256, 0, stream>>>(k, Wk, bk, Kh, 1);
  gemm_bias_kernel<<<gemm_grid, 256, 0, stream>>>(v, Wv, bv, Vh, 1);

  flash_attn_kernel<<<BATCH * HEADS * (SLEN / 64), 256, 0, stream>>>(
      Qh, Kh, Vh, mask, Xa);

  gemm_bias_kernel<<<gemm_grid, 256, 0, stream>>>(Xa, Wo, bo, out, 0);
}

// Round 2
// 908.395 us; speedup vs baseline: 2.2913x; 2.2913x over previous
//
#include <hip/hip_runtime.h>
#include <hip/hip_bf16.h>
#include <math.h>

#define HIDDEN 1024
#define HEADS 16
#define DK 64
#define BATCH 2
#define SLEN 2048

typedef __attribute__((ext_vector_type(8))) short short8v;
typedef __attribute__((ext_vector_type(4))) float f32x4;

__device__ __forceinline__ unsigned short bf_hi(float x) {
  unsigned u = __builtin_bit_cast(unsigned, x);
  unsigned r = u + 0x7fffu + ((u >> 16) & 1u);
  return (unsigned short)(r >> 16);
}
__device__ __forceinline__ float bf_f(unsigned short h) {
  unsigned u = ((unsigned)h) << 16;
  return __builtin_bit_cast(float, u);
}

// ---------------------------------------------------------------------------
// GEMM: Y = A @ W + bias.  A: [4096][1024], W: [1024][1024].
// mode 0: Yf[m][n] fp32
// mode 1: Yhi/Ylo bf16 split, head-split [bh][s][d]
// mode 2: Yhi/Ylo bf16 split, head-split TRANSPOSED [bh*64+d][s]  (for V)
// ---------------------------------------------------------------------------
__global__ __launch_bounds__(256) void gemm_bias_kernel(
    const float* __restrict__ A, const float* __restrict__ W,
    const float* __restrict__ bias, unsigned short* __restrict__ Yhi,
    unsigned short* __restrict__ Ylo, float* __restrict__ Yf, int mode)
{
  __shared__ float As[16][68];
  __shared__ float Bs[16][68];

  const int tid = threadIdx.x;
  const int bm = blockIdx.x >> 4;
  const int bn = blockIdx.x & 15;
  const int m0 = bm * 64, n0 = bn * 64;
  const int tm = tid & 15;
  const int tn = tid >> 4;

  const int arow = tid >> 2, acol = (tid & 3) << 2;
  const int brow = tid >> 4, bcol = (tid & 15) << 2;

  float acc[4][4];
#pragma unroll
  for (int i = 0; i < 4; ++i)
#pragma unroll
    for (int j = 0; j < 4; ++j) acc[i][j] = 0.f;

  for (int k0 = 0; k0 < HIDDEN; k0 += 16) {
    float4 a = *(const float4*)(A + (size_t)(m0 + arow) * HIDDEN + k0 + acol);
    As[acol + 0][arow] = a.x;
    As[acol + 1][arow] = a.y;
    As[acol + 2][arow] = a.z;
    As[acol + 3][arow] = a.w;
    *(float4*)&Bs[brow][bcol] =
        *(const float4*)(W + (size_t)(k0 + brow) * HIDDEN + n0 + bcol);
    __syncthreads();

#pragma unroll
    for (int kk = 0; kk < 16; ++kk) {
      float4 av = *(const float4*)&As[kk][tm * 4];
      float4 bv = *(const float4*)&Bs[kk][tn * 4];
      float ar[4] = {av.x, av.y, av.z, av.w};
      float br[4] = {bv.x, bv.y, bv.z, bv.w};
#pragma unroll
      for (int i = 0; i < 4; ++i)
#pragma unroll
        for (int j = 0; j < 4; ++j) acc[i][j] += ar[i] * br[j];
    }
    __syncthreads();
  }

  const int n = n0 + tn * 4;
  float b0 = bias[n + 0], b1 = bias[n + 1], b2 = bias[n + 2], b3 = bias[n + 3];
#pragma unroll
  for (int i = 0; i < 4; ++i) {
    int m = m0 + tm * 4 + i;
    float v0 = acc[i][0] + b0, v1 = acc[i][1] + b1;
    float v2 = acc[i][2] + b2, v3 = acc[i][3] + b3;
    if (mode == 0) {
      float4 o4 = {v0, v1, v2, v3};
      *(float4*)(Yf + (size_t)m * HIDDEN + n) = o4;
    } else {
      int bb = m >> 11, s = m & (SLEN - 1), hh = n >> 6, d0 = n & 63;
      unsigned short h0 = bf_hi(v0), h1 = bf_hi(v1);
      unsigned short h2 = bf_hi(v2), h3 = bf_hi(v3);
      unsigned short l0 = bf_hi(v0 - bf_f(h0)), l1 = bf_hi(v1 - bf_f(h1));
      unsigned short l2 = bf_hi(v2 - bf_f(h2)), l3 = bf_hi(v3 - bf_f(h3));
      if (mode == 1) {
        size_t base = (((size_t)(bb * HEADS + hh) * SLEN + s) << 6) + d0;
        ushort4 H = {h0, h1, h2, h3};
        ushort4 L = {l0, l1, l2, l3};
        *(ushort4*)(Yhi + base) = H;
        *(ushort4*)(Ylo + base) = L;
      } else {
        size_t rb = ((size_t)((bb * HEADS + hh) * DK + d0)) * SLEN + s;
        Yhi[rb + 0 * SLEN] = h0; Yhi[rb + 1 * SLEN] = h1;
        Yhi[rb + 2 * SLEN] = h2; Yhi[rb + 3 * SLEN] = h3;
        Ylo[rb + 0 * SLEN] = l0; Ylo[rb + 1 * SLEN] = l1;
        Ylo[rb + 2 * SLEN] = l2; Ylo[rb + 3 * SLEN] = l3;
      }
    }
  }
}

// ---------------------------------------------------------------------------
// MFMA flash attention, split-precision bf16 (hi+lo), 16x16x32 MFMA.
// Block = 4 waves; wave w owns q-rows [qt*64+w*16, +16). KV step = 64.
// K LDS [k][d] and V LDS [d][k] (V pre-transposed in ws), XOR-swizzled.
// Softmax per wave: C-frag rows q=4g+r reduced over 16 lanes via shfl_xor.
// P goes through wave-private LDS (packed hi|lo u32) to form PV A-frags.
// ---------------------------------------------------------------------------
__global__ __launch_bounds__(256) void attn_mfma_kernel(
    const unsigned short* __restrict__ Qhi, const unsigned short* __restrict__ Qlo,
    const unsigned short* __restrict__ Khi, const unsigned short* __restrict__ Klo,
    const unsigned short* __restrict__ Vthi, const unsigned short* __restrict__ Vtlo,
    const int* __restrict__ mask, float* __restrict__ Xa)
{
  __shared__ __align__(16) unsigned short Ks_hi[64 * 64], Ks_lo[64 * 64];
  __shared__ __align__(16) unsigned short Vs_hi[64 * 64], Vs_lo[64 * 64];
  __shared__ unsigned P_s[4][16 * 64];

  const int tid = threadIdx.x;
  const int bx = blockIdx.x;
  const int lb = (bx & 7) * 128 + (bx >> 3);  // XCD swizzle, bijective (1024%8==0)
  const int qt = lb & 31;
  const int bh = lb >> 5;
  const int b = bh >> 4, h = bh & 15;
  const int w = tid >> 6, lane = tid & 63;
  const int g = lane >> 4, qi = lane & 15;
  const int qbase = qt * 64 + w * 16;

  // Q fragments (held for whole kernel): A[row=qi][d=dh*32+8g+j]
  short8v qh[2], ql[2];
  {
    const unsigned short* qr_hi = Qhi + ((size_t)bh * SLEN + qbase + qi) * DK;
    const unsigned short* qr_lo = Qlo + ((size_t)bh * SLEN + qbase + qi) * DK;
    qh[0] = *(const short8v*)(qr_hi + g * 8);
    qh[1] = *(const short8v*)(qr_hi + 32 + g * 8);
    ql[0] = *(const short8v*)(qr_lo + g * 8);
    ql[1] = *(const short8v*)(qr_lo + 32 + g * 8);
  }

  f32x4 o[4];
  float m_run[4], l_run[4];
#pragma unroll
  for (int dt = 0; dt < 4; ++dt) { o[dt][0]=0.f; o[dt][1]=0.f; o[dt][2]=0.f; o[dt][3]=0.f; }
#pragma unroll
  for (int r = 0; r < 4; ++r) { m_run[r] = -INFINITY; l_run[r] = 0.f; }

  const int qrow_g = qbase + g * 4;  // this lane's rows: qrow_g + r
  const int* mbase = mask + (size_t)b * SLEN * SLEN;

  for (int k0 = 0; k0 < SLEN; k0 += 64) {
    __syncthreads();
    // stage K (hi/lo) [k][d] and Vt (hi/lo) [d][k], swizzled (elem ^= (row&7)<<3)
    {
      int row = tid >> 3, sl = (tid & 7) * 8;
#pragma unroll
      for (int i = 0; i < 2; ++i) {
        int r2 = row + i * 32;
        size_t gkv = ((size_t)bh * SLEN + k0 + r2) * DK + sl;
        size_t gvt = ((size_t)(bh * DK + r2)) * SLEN + k0 + sl;
        int di = r2 * 64 + (sl ^ ((r2 & 7) << 3));
        *(int4*)&Ks_hi[di] = *(const int4*)(Khi + gkv);
        *(int4*)&Ks_lo[di] = *(const int4*)(Klo + gkv);
        *(int4*)&Vs_hi[di] = *(const int4*)(Vthi + gvt);
        *(int4*)&Vs_lo[di] = *(const int4*)(Vtlo + gvt);
      }
    }
    __syncthreads();

    // QK^T: S = Qhi*Khi + Qhi*Klo + Qlo*Khi   (2 d-halves each)
    f32x4 sf[4];
#pragma unroll
    for (int ks = 0; ks < 4; ++ks) {
      int krow = ks * 16 + qi;
      int cswz = (krow & 7) << 3;
      short8v kh0 = *(const short8v*)&Ks_hi[krow * 64 + ((g * 8) ^ cswz)];
      short8v kh1 = *(const short8v*)&Ks_hi[krow * 64 + ((32 + g * 8) ^ cswz)];
      short8v kl0 = *(const short8v*)&Ks_lo[krow * 64 + ((g * 8) ^ cswz)];
      short8v kl1 = *(const short8v*)&Ks_lo[krow * 64 + ((32 + g * 8) ^ cswz)];
      f32x4 s = {0.f, 0.f, 0.f, 0.f};
      s = __builtin_amdgcn_mfma_f32_16x16x32_bf16(qh[0], kh0, s, 0, 0, 0);
      s = __builtin_amdgcn_mfma_f32_16x16x32_bf16(qh[1], kh1, s, 0, 0, 0);
      s = __builtin_amdgcn_mfma_f32_16x16x32_bf16(ql[0], kh0, s, 0, 0, 0);
      s = __builtin_amdgcn_mfma_f32_16x16x32_bf16(ql[1], kh1, s, 0, 0, 0);
      s = __builtin_amdgcn_mfma_f32_16x16x32_bf16(qh[0], kl0, s, 0, 0, 0);
      s = __builtin_amdgcn_mfma_f32_16x16x32_bf16(qh[1], kl1, s, 0, 0, 0);
      sf[ks] = s;
    }

    // mask + online softmax (rows q=4g+r live in 16-lane group g at cols qi)
    float p_all[4][4];
#pragma unroll
    for (int r = 0; r < 4; ++r) {
      const int* mr = mbase + (size_t)(qrow_g + r) * SLEN + k0;
      float sv[4];
#pragma unroll
      for (int ks = 0; ks < 4; ++ks) {
        float x = sf[ks][r] * 0.125f;  // 1/sqrt(64)
        sv[ks] = (mr[ks * 16 + qi] == 0) ? -INFINITY : x;
      }
      float tmax = fmaxf(fmaxf(sv[0], sv[1]), fmaxf(sv[2], sv[3]));
      tmax = fmaxf(tmax, __shfl_xor(tmax, 1));
      tmax = fmaxf(tmax, __shfl_xor(tmax, 2));
      tmax = fmaxf(tmax, __shfl_xor(tmax, 4));
      tmax = fmaxf(tmax, __shfl_xor(tmax, 8));
      float mnew = fmaxf(m_run[r], tmax);
      if (mnew == -INFINITY) {
        p_all[r][0] = p_all[r][1] = p_all[r][2] = p_all[r][3] = 0.f;
      } else {
        float scale = __expf(m_run[r] - mnew);  // 0 when m_run==-inf
        l_run[r] *= scale;
        o[0][r] *= scale; o[1][r] *= scale; o[2][r] *= scale; o[3][r] *= scale;
        float lsum = 0.f;
#pragma unroll
        for (int ks = 0; ks < 4; ++ks) {
          float pv = __expf(sv[ks] - mnew);
          p_all[r][ks] = pv;
          lsum += pv;
        }
        lsum += __shfl_xor(lsum, 1);
        lsum += __shfl_xor(lsum, 2);
        lsum += __shfl_xor(lsum, 4);
        lsum += __shfl_xor(lsum, 8);
        l_run[r] += lsum;
        m_run[r] = mnew;
      }
    }

    // P -> wave-private LDS as packed (hi | lo<<16) u32, swizzled
    unsigned* Pw = P_s[w];
#pragma unroll
    for (int r = 0; r < 4; ++r) {
      int q = g * 4 + r;
      int rs = q * 64, xs = (q & 7) << 2;
#pragma unroll
      for (int ks = 0; ks < 4; ++ks) {
        float pv = p_all[r][ks];
        unsigned short hi = bf_hi(pv);
        unsigned short lo = bf_hi(pv - bf_f(hi));
        Pw[rs + ((ks * 16 + qi) ^ xs)] = (unsigned)hi | ((unsigned)lo << 16);
      }
    }

    // PV: O += Phi*Vhi + Phi*Vlo + Plo*Vhi  (2 k-halves of 32)
#pragma unroll
    for (int kh = 0; kh < 2; ++kh) {
      int cb = kh * 32 + g * 8;
      int base = qi * 64, xs = (qi & 7) << 2;
      uint4 pa = *(const uint4*)&Pw[base + (cb ^ xs)];
      uint4 pb = *(const uint4*)&Pw[base + ((cb + 4) ^ xs)];
      unsigned u[8] = {pa.x, pa.y, pa.z, pa.w, pb.x, pb.y, pb.z, pb.w};
      short8v phi, plo;
#pragma unroll
      for (int j2 = 0; j2 < 8; ++j2) {
        phi[j2] = (short)(u[j2] & 0xffff);
        plo[j2] = (short)(u[j2] >> 16);
      }
#pragma unroll
      for (int dt = 0; dt < 4; ++dt) {
        int drow = dt * 16 + qi;
        int vcol = (kh * 32 + g * 8) ^ ((drow & 7) << 3);
        short8v vh = *(const short8v*)&Vs_hi[drow * 64 + vcol];
        short8v vl = *(const short8v*)&Vs_lo[drow * 64 + vcol];
        o[dt] = __builtin_amdgcn_mfma_f32_16x16x32_bf16(phi, vh, o[dt], 0, 0, 0);
        o[dt] = __builtin_amdgcn_mfma_f32_16x16x32_bf16(phi, vl, o[dt], 0, 0, 0);
        o[dt] = __builtin_amdgcn_mfma_f32_16x16x32_bf16(plo, vh, o[dt], 0, 0, 0);
      }
    }
  }

  // normalize + write Xa [b][s][h*64+d]
#pragma unroll
  for (int r = 0; r < 4; ++r) {
    float inv = l_run[r] > 0.f ? 1.f / l_run[r] : 0.f;
    float* xr = Xa + ((size_t)(b * SLEN) + qrow_g + r) * HIDDEN + h * DK;
#pragma unroll
    for (int dt = 0; dt < 4; ++dt) xr[dt * 16 + qi] = o[dt][r] * inv;
  }
}

// ---------------------------------------------------------------------------
extern "C" void kernel_launch(void* const* d_in, const int* in_sizes, int n_in,
                              void* d_out, int out_size, void* d_ws, size_t ws_size,
                              hipStream_t stream) {
  const float* q   = (const float*)d_in[0];
  const float* k   = (const float*)d_in[1];
  const float* v   = (const float*)d_in[2];
  const int*  mask = (const int*)d_in[3];
  const float* Wq  = (const float*)d_in[4];
  const float* bq  = (const float*)d_in[5];
  const float* Wk  = (const float*)d_in[6];
  const float* bk  = (const float*)d_in[7];
  const float* Wv  = (const float*)d_in[8];
  const float* bv  = (const float*)d_in[9];
  const float* Wo  = (const float*)d_in[10];
  const float* bo  = (const float*)d_in[11];
  float* out = (float*)d_out;

  const size_t HSZ = (size_t)BATCH * SLEN * HIDDEN;  // 4,194,304
  unsigned short* wsu = (unsigned short*)d_ws;
  unsigned short* Qhi = wsu;
  unsigned short* Qlo = wsu + HSZ;
  unsigned short* Khi = wsu + 2 * HSZ;
  unsigned short* Klo = wsu + 3 * HSZ;
  unsigned short* Vthi = wsu + 4 * HSZ;
  unsigned short* Vtlo = wsu + 5 * HSZ;
  float* Xa = (float*)(wsu + 6 * HSZ);

  gemm_bias_kernel<<<1024, 256, 0, stream>>>(q, Wq, bq, Qhi, Qlo, nullptr, 1);
  gemm_bias_kernel<<<1024, 256, 0, stream>>>(k, Wk, bk, Khi, Klo, nullptr, 1);
  gemm_bias_kernel<<<1024, 256, 0, stream>>>(v, Wv, bv, Vthi, Vtlo, nullptr, 2);

  attn_mfma_kernel<<<1024, 256, 0, stream>>>(Qhi, Qlo, Khi, Klo, Vthi, Vtlo,
                                             mask, Xa);

  gemm_bias_kernel<<<1024, 256, 0, stream>>>(Xa, Wo, bo, nullptr, nullptr, out, 0);
}

// Round 4
// 608.694 us; speedup vs baseline: 3.4195x; 1.4924x over previous
//
#include <hip/hip_runtime.h>
#include <hip/hip_bf16.h>
#include <math.h>

#define HIDDEN 1024
#define HEADS 16
#define DK 64
#define BATCH 2
#define SLEN 2048

typedef __attribute__((ext_vector_type(8))) short short8v;
typedef __attribute__((ext_vector_type(4))) float f32x4;

__device__ __forceinline__ unsigned short bf_hi(float x) {
  unsigned u = __builtin_bit_cast(unsigned, x);
  unsigned r = u + 0x7fffu + ((u >> 16) & 1u);
  return (unsigned short)(r >> 16);
}
__device__ __forceinline__ float bf_f(unsigned short h) {
  unsigned u = ((unsigned)h) << 16;
  return __builtin_bit_cast(float, u);
}
__device__ __forceinline__ unsigned pack_hl(float x) {
  unsigned short hi = bf_hi(x);
  unsigned short lo = bf_hi(x - bf_f(hi));
  return (unsigned)hi | ((unsigned)lo << 16);
}

// unpack two uint4 (8 packed u32, k ascending) into hi or lo short8v
__device__ __forceinline__ short8v unpack8(const uint4& a0, const uint4& a1,
                                           unsigned sel) {
  uint4 r;
  r.x = __builtin_amdgcn_perm(a0.y, a0.x, sel);
  r.y = __builtin_amdgcn_perm(a0.w, a0.z, sel);
  r.z = __builtin_amdgcn_perm(a1.y, a1.x, sel);
  r.w = __builtin_amdgcn_perm(a1.w, a1.z, sel);
  return __builtin_bit_cast(short8v, r);
}
#define SEL_HI 0x05040100u
#define SEL_LO 0x07060302u

#define GLB_U(p) ((const __attribute__((address_space(1))) unsigned*)(p))
#define LDS_U(p) ((__attribute__((address_space(3))) unsigned*)(p))

// ---------------------------------------------------------------------------
// pack fp32 -> u32 (bf16 hi | lo<<16), elementwise, float4 vectorized
// ---------------------------------------------------------------------------
__global__ __launch_bounds__(256) void pack_act_kernel(
    const float* __restrict__ src, unsigned* __restrict__ dst, int n4)
{
  int stride = gridDim.x * blockDim.x;
  for (int i = blockIdx.x * blockDim.x + threadIdx.x; i < n4; i += stride) {
    float4 v = ((const float4*)src)[i];
    uint4 o;
    o.x = pack_hl(v.x); o.y = pack_hl(v.y);
    o.z = pack_hl(v.z); o.w = pack_hl(v.w);
    ((uint4*)dst)[i] = o;
  }
}

// ---------------------------------------------------------------------------
// pack + transpose weight: W[k][n] fp32 -> Wt[n][k] packed u32. 64x64 tiles.
// ---------------------------------------------------------------------------
__global__ __launch_bounds__(256) void pack_wT_kernel(
    const float* __restrict__ W, unsigned* __restrict__ Wt)
{
  __shared__ float T[64][65];
  const int t = threadIdx.x;
  const int bk = blockIdx.x >> 4, bn = blockIdx.x & 15;
#pragma unroll
  for (int i = 0; i < 4; ++i) {
    int k = (t >> 4) + i * 16, n = (t & 15) * 4;
    float4 v = *(const float4*)(W + (size_t)(bk * 64 + k) * HIDDEN + bn * 64 + n);
    T[k][n + 0] = v.x; T[k][n + 1] = v.y; T[k][n + 2] = v.z; T[k][n + 3] = v.w;
  }
  __syncthreads();
  const int nl = t & 63, kc = (t >> 6) * 16;
#pragma unroll
  for (int i = 0; i < 4; ++i) {
    uint4 o;
    o.x = pack_hl(T[kc + i * 4 + 0][nl]);
    o.y = pack_hl(T[kc + i * 4 + 1][nl]);
    o.z = pack_hl(T[kc + i * 4 + 2][nl]);
    o.w = pack_hl(T[kc + i * 4 + 3][nl]);
    *(uint4*)(Wt + (size_t)(bn * 64 + nl) * HIDDEN + bk * 64 + kc + i * 4) = o;
  }
}

// ---------------------------------------------------------------------------
// Split-precision bf16 MFMA GEMM on packed-u32 inputs.
// C = A @ Bt^T + bias;  A: [4096][1024] pk, Bt: [1024 n][1024 k] pk.
// Tile 128m x 64n, BK=32, 4 waves (2x2, each 64x32), 16x16x32 MFMA, 3 products.
// LDS rows = 32 u32 = 128B, chunk-XOR swizzle (c ^= r&7); staged with
// global_load_lds (linear dest, inverse-swizzled per-lane source).
// mode 0: Yf[m][n] fp32.  mode 1: Yhi/Ylo [bh][s][d].  mode 2: [bh*64+d][s].
// ---------------------------------------------------------------------------
__global__ __launch_bounds__(256) void gemm_pk_kernel(
    const unsigned* __restrict__ A, const unsigned* __restrict__ Bt,
    const float* __restrict__ bias, unsigned short* __restrict__ Yhi,
    unsigned short* __restrict__ Ylo, float* __restrict__ Yf, int mode)
{
  __shared__ __align__(16) unsigned Al[128 * 32];  // 16KB
  __shared__ __align__(16) unsigned Bl[64 * 32];   // 8KB

  const int tid = threadIdx.x;
  const int bx = blockIdx.x;
  const int lb = (bx & 7) * 64 + (bx >> 3);  // XCD swizzle (512 % 8 == 0)
  const int bm = lb >> 4, bn = lb & 15;
  const int m0 = bm * 128, n0 = bn * 64;
  const int w = tid >> 6, lane = tid & 63;
  const int wm = w >> 1, wn = w & 1;
  const int g = lane >> 4, qi = lane & 15;
  const int p0 = (2 * g) ^ (qi & 7);

  f32x4 acc[4][2];
#pragma unroll
  for (int mt = 0; mt < 4; ++mt)
#pragma unroll
    for (int nt = 0; nt < 2; ++nt) acc[mt][nt] = (f32x4){0.f, 0.f, 0.f, 0.f};

  for (int k0 = 0; k0 < HIDDEN; k0 += 32) {
    __syncthreads();
    // stage A (1024 chunks) + B (512 chunks), 16B each
#pragma unroll
    for (int i = 0; i < 4; ++i) {
      int chunk = tid + i * 256;
      int r = chunk >> 3, c = chunk & 7;
      const unsigned* src = A + (size_t)(m0 + r) * HIDDEN + k0 + ((c ^ (r & 7)) << 2);
      __builtin_amdgcn_global_load_lds(GLB_U(src), LDS_U(Al + chunk * 4), 16, 0, 0);
    }
#pragma unroll
    for (int i = 0; i < 2; ++i) {
      int chunk = tid + i * 256;
      int r = chunk >> 3, c = chunk & 7;
      const unsigned* src = Bt + (size_t)(n0 + r) * HIDDEN + k0 + ((c ^ (r & 7)) << 2);
      __builtin_amdgcn_global_load_lds(GLB_U(src), LDS_U(Bl + chunk * 4), 16, 0, 0);
    }
    __syncthreads();

    short8v ah[4], al[4];
#pragma unroll
    for (int mt = 0; mt < 4; ++mt) {
      const unsigned* Ar = Al + (wm * 64 + mt * 16 + qi) * 32;
      uint4 a0 = *(const uint4*)(Ar + p0 * 4);
      uint4 a1 = *(const uint4*)(Ar + (p0 ^ 1) * 4);
      ah[mt] = unpack8(a0, a1, SEL_HI);
      al[mt] = unpack8(a0, a1, SEL_LO);
    }
#pragma unroll
    for (int nt = 0; nt < 2; ++nt) {
      const unsigned* Br = Bl + (wn * 32 + nt * 16 + qi) * 32;
      uint4 b0 = *(const uint4*)(Br + p0 * 4);
      uint4 b1 = *(const uint4*)(Br + (p0 ^ 1) * 4);
      short8v bh = unpack8(b0, b1, SEL_HI);
      short8v bl = unpack8(b0, b1, SEL_LO);
#pragma unroll
      for (int mt = 0; mt < 4; ++mt) {
        acc[mt][nt] = __builtin_amdgcn_mfma_f32_16x16x32_bf16(ah[mt], bh, acc[mt][nt], 0, 0, 0);
        acc[mt][nt] = __builtin_amdgcn_mfma_f32_16x16x32_bf16(al[mt], bh, acc[mt][nt], 0, 0, 0);
        acc[mt][nt] = __builtin_amdgcn_mfma_f32_16x16x32_bf16(ah[mt], bl, acc[mt][nt], 0, 0, 0);
      }
    }
  }

  // epilogue
#pragma unroll
  for (int nt = 0; nt < 2; ++nt) {
    int n = n0 + wn * 32 + nt * 16 + qi;
    float bv = bias[n];
#pragma unroll
    for (int mt = 0; mt < 4; ++mt) {
#pragma unroll
      for (int r = 0; r < 4; ++r) {
        int m = m0 + wm * 64 + mt * 16 + g * 4 + r;
        float val = acc[mt][nt][r] + bv;
        if (mode == 0) {
          Yf[(size_t)m * HIDDEN + n] = val;
        } else {
          int s = m & (SLEN - 1);
          int bh_ = (m >> 11) * HEADS + (n >> 6);
          int d = n & 63;
          unsigned short hi = bf_hi(val);
          unsigned short lo = bf_hi(val - bf_f(hi));
          size_t base = (mode == 1) ? (((size_t)bh_ * SLEN + s) << 6) + d
                                    : ((size_t)(bh_ * DK + d)) * SLEN + s;
          Yhi[base] = hi;
          Ylo[base] = lo;
        }
      }
    }
  }
}

// ---------------------------------------------------------------------------
// MFMA flash attention, split-precision bf16 (unchanged from round 2 except
// the epilogue now writes packed u32 Xa for the final GEMM).
// ---------------------------------------------------------------------------
__global__ __launch_bounds__(256) void attn_mfma_kernel(
    const unsigned short* __restrict__ Qhi, const unsigned short* __restrict__ Qlo,
    const unsigned short* __restrict__ Khi, const unsigned short* __restrict__ Klo,
    const unsigned short* __restrict__ Vthi, const unsigned short* __restrict__ Vtlo,
    const int* __restrict__ mask, unsigned* __restrict__ XaPk)
{
  __shared__ __align__(16) unsigned short Ks_hi[64 * 64], Ks_lo[64 * 64];
  __shared__ __align__(16) unsigned short Vs_hi[64 * 64], Vs_lo[64 * 64];
  __shared__ unsigned P_s[4][16 * 64];

  const int tid = threadIdx.x;
  const int bx = blockIdx.x;
  const int lb = (bx & 7) * 128 + (bx >> 3);
  const int qt = lb & 31;
  const int bh = lb >> 5;
  const int b = bh >> 4, h = bh & 15;
  const int w = tid >> 6, lane = tid & 63;
  const int g = lane >> 4, qi = lane & 15;
  const int qbase = qt * 64 + w * 16;

  short8v qh[2], ql[2];
  {
    const unsigned short* qr_hi = Qhi + ((size_t)bh * SLEN + qbase + qi) * DK;
    const unsigned short* qr_lo = Qlo + ((size_t)bh * SLEN + qbase + qi) * DK;
    qh[0] = *(const short8v*)(qr_hi + g * 8);
    qh[1] = *(const short8v*)(qr_hi + 32 + g * 8);
    ql[0] = *(const short8v*)(qr_lo + g * 8);
    ql[1] = *(const short8v*)(qr_lo + 32 + g * 8);
  }

  f32x4 o[4];
  float m_run[4], l_run[4];
#pragma unroll
  for (int dt = 0; dt < 4; ++dt) { o[dt][0]=0.f; o[dt][1]=0.f; o[dt][2]=0.f; o[dt][3]=0.f; }
#pragma unroll
  for (int r = 0; r < 4; ++r) { m_run[r] = -INFINITY; l_run[r] = 0.f; }

  const int qrow_g = qbase + g * 4;
  const int* mbase = mask + (size_t)b * SLEN * SLEN;

  for (int k0 = 0; k0 < SLEN; k0 += 64) {
    __syncthreads();
    {
      int row = tid >> 3, sl = (tid & 7) * 8;
#pragma unroll
      for (int i = 0; i < 2; ++i) {
        int r2 = row + i * 32;
        size_t gkv = ((size_t)bh * SLEN + k0 + r2) * DK + sl;
        size_t gvt = ((size_t)(bh * DK + r2)) * SLEN + k0 + sl;
        int di = r2 * 64 + (sl ^ ((r2 & 7) << 3));
        *(int4*)&Ks_hi[di] = *(const int4*)(Khi + gkv);
        *(int4*)&Ks_lo[di] = *(const int4*)(Klo + gkv);
        *(int4*)&Vs_hi[di] = *(const int4*)(Vthi + gvt);
        *(int4*)&Vs_lo[di] = *(const int4*)(Vtlo + gvt);
      }
    }
    __syncthreads();

    f32x4 sf[4];
#pragma unroll
    for (int ks = 0; ks < 4; ++ks) {
      int krow = ks * 16 + qi;
      int cswz = (krow & 7) << 3;
      short8v kh0 = *(const short8v*)&Ks_hi[krow * 64 + ((g * 8) ^ cswz)];
      short8v kh1 = *(const short8v*)&Ks_hi[krow * 64 + ((32 + g * 8) ^ cswz)];
      short8v kl0 = *(const short8v*)&Ks_lo[krow * 64 + ((g * 8) ^ cswz)];
      short8v kl1 = *(const short8v*)&Ks_lo[krow * 64 + ((32 + g * 8) ^ cswz)];
      f32x4 s = {0.f, 0.f, 0.f, 0.f};
      s = __builtin_amdgcn_mfma_f32_16x16x32_bf16(qh[0], kh0, s, 0, 0, 0);
      s = __builtin_amdgcn_mfma_f32_16x16x32_bf16(qh[1], kh1, s, 0, 0, 0);
      s = __builtin_amdgcn_mfma_f32_16x16x32_bf16(ql[0], kh0, s, 0, 0, 0);
      s = __builtin_amdgcn_mfma_f32_16x16x32_bf16(ql[1], kh1, s, 0, 0, 0);
      s = __builtin_amdgcn_mfma_f32_16x16x32_bf16(qh[0], kl0, s, 0, 0, 0);
      s = __builtin_amdgcn_mfma_f32_16x16x32_bf16(qh[1], kl1, s, 0, 0, 0);
      sf[ks] = s;
    }

    float p_all[4][4];
#pragma unroll
    for (int r = 0; r < 4; ++r) {
      const int* mr = mbase + (size_t)(qrow_g + r) * SLEN + k0;
      float sv[4];
#pragma unroll
      for (int ks = 0; ks < 4; ++ks) {
        float x = sf[ks][r] * 0.125f;
        sv[ks] = (mr[ks * 16 + qi] == 0) ? -INFINITY : x;
      }
      float tmax = fmaxf(fmaxf(sv[0], sv[1]), fmaxf(sv[2], sv[3]));
      tmax = fmaxf(tmax, __shfl_xor(tmax, 1));
      tmax = fmaxf(tmax, __shfl_xor(tmax, 2));
      tmax = fmaxf(tmax, __shfl_xor(tmax, 4));
      tmax = fmaxf(tmax, __shfl_xor(tmax, 8));
      float mnew = fmaxf(m_run[r], tmax);
      if (mnew == -INFINITY) {
        p_all[r][0] = p_all[r][1] = p_all[r][2] = p_all[r][3] = 0.f;
      } else {
        float scale = __expf(m_run[r] - mnew);
        l_run[r] *= scale;
        o[0][r] *= scale; o[1][r] *= scale; o[2][r] *= scale; o[3][r] *= scale;
        float lsum = 0.f;
#pragma unroll
        for (int ks = 0; ks < 4; ++ks) {
          float pv = __expf(sv[ks] - mnew);
          p_all[r][ks] = pv;
          lsum += pv;
        }
        lsum += __shfl_xor(lsum, 1);
        lsum += __shfl_xor(lsum, 2);
        lsum += __shfl_xor(lsum, 4);
        lsum += __shfl_xor(lsum, 8);
        l_run[r] += lsum;
        m_run[r] = mnew;
      }
    }

    unsigned* Pw = P_s[w];
#pragma unroll
    for (int r = 0; r < 4; ++r) {
      int q = g * 4 + r;
      int rs = q * 64, xs = (q & 7) << 2;
#pragma unroll
      for (int ks = 0; ks < 4; ++ks) {
        float pv = p_all[r][ks];
        unsigned short hi = bf_hi(pv);
        unsigned short lo = bf_hi(pv - bf_f(hi));
        Pw[rs + ((ks * 16 + qi) ^ xs)] = (unsigned)hi | ((unsigned)lo << 16);
      }
    }

#pragma unroll
    for (int kh = 0; kh < 2; ++kh) {
      int cb = kh * 32 + g * 8;
      int base = qi * 64, xs = (qi & 7) << 2;
      uint4 pa = *(const uint4*)&Pw[base + (cb ^ xs)];
      uint4 pb = *(const uint4*)&Pw[base + ((cb + 4) ^ xs)];
      unsigned u[8] = {pa.x, pa.y, pa.z, pa.w, pb.x, pb.y, pb.z, pb.w};
      short8v phi, plo;
#pragma unroll
      for (int j2 = 0; j2 < 8; ++j2) {
        phi[j2] = (short)(u[j2] & 0xffff);
        plo[j2] = (short)(u[j2] >> 16);
      }
#pragma unroll
      for (int dt = 0; dt < 4; ++dt) {
        int drow = dt * 16 + qi;
        int vcol = (kh * 32 + g * 8) ^ ((drow & 7) << 3);
        short8v vh = *(const short8v*)&Vs_hi[drow * 64 + vcol];
        short8v vl = *(const short8v*)&Vs_lo[drow * 64 + vcol];
        o[dt] = __builtin_amdgcn_mfma_f32_16x16x32_bf16(phi, vh, o[dt], 0, 0, 0);
        o[dt] = __builtin_amdgcn_mfma_f32_16x16x32_bf16(phi, vl, o[dt], 0, 0, 0);
        o[dt] = __builtin_amdgcn_mfma_f32_16x16x32_bf16(plo, vh, o[dt], 0, 0, 0);
      }
    }
  }

  // normalize + write packed Xa [b*S+s][h*64+d] (u32 hi|lo)
#pragma unroll
  for (int r = 0; r < 4; ++r) {
    float inv = l_run[r] > 0.f ? 1.f / l_run[r] : 0.f;
    unsigned* xr = XaPk + ((size_t)(b * SLEN) + qrow_g + r) * HIDDEN + h * DK;
#pragma unroll
    for (int dt = 0; dt < 4; ++dt) xr[dt * 16 + qi] = pack_hl(o[dt][r] * inv);
  }
}

// ---------------------------------------------------------------------------
extern "C" void kernel_launch(void* const* d_in, const int* in_sizes, int n_in,
                              void* d_out, int out_size, void* d_ws, size_t ws_size,
                              hipStream_t stream) {
  const float* q   = (const float*)d_in[0];
  const float* k   = (const float*)d_in[1];
  const float* v   = (const float*)d_in[2];
  const int*  mask = (const int*)d_in[3];
  const float* Wq  = (const float*)d_in[4];
  const float* bq  = (const float*)d_in[5];
  const float* Wk  = (const float*)d_in[6];
  const float* bk  = (const float*)d_in[7];
  const float* Wv  = (const float*)d_in[8];
  const float* bv  = (const float*)d_in[9];
  const float* Wo  = (const float*)d_in[10];
  const float* bo  = (const float*)d_in[11];
  float* out = (float*)d_out;

  const size_t HSZ = (size_t)BATCH * SLEN * HIDDEN;  // 4,194,304 elems
  unsigned short* wsu = (unsigned short*)d_ws;
  unsigned short* Qhi = wsu;
  unsigned short* Qlo = wsu + HSZ;
  unsigned short* Khi = wsu + 2 * HSZ;
  unsigned short* Klo = wsu + 3 * HSZ;
  unsigned short* Vthi = wsu + 4 * HSZ;
  unsigned short* Vtlo = wsu + 5 * HSZ;
  unsigned* Apk = (unsigned*)(wsu + 6 * HSZ);        // 16MB, reused; aliases XaPk
  unsigned* WtPk = Apk + HSZ;                        // 4MB, reused
  unsigned* XaPk = Apk;

  const int n4 = (int)(HSZ / 4);

  // Q projection
  pack_act_kernel<<<1024, 256, 0, stream>>>(q, Apk, n4);
  pack_wT_kernel<<<256, 256, 0, stream>>>(Wq, WtPk);
  gemm_pk_kernel<<<512, 256, 0, stream>>>(Apk, WtPk, bq, Qhi, Qlo, nullptr, 1);
  // K projection
  pack_act_kernel<<<1024, 256, 0, stream>>>(k, Apk, n4);
  pack_wT_kernel<<<256, 256, 0, stream>>>(Wk, WtPk);
  gemm_pk_kernel<<<512, 256, 0, stream>>>(Apk, WtPk, bk, Khi, Klo, nullptr, 1);
  // V projection (transposed output)
  pack_act_kernel<<<1024, 256, 0, stream>>>(v, Apk, n4);
  pack_wT_kernel<<<256, 256, 0, stream>>>(Wv, WtPk);
  gemm_pk_kernel<<<512, 256, 0, stream>>>(Apk, WtPk, bv, Vthi, Vtlo, nullptr, 2);
  // attention -> packed Xa (reuses Apk buffer)
  attn_mfma_kernel<<<1024, 256, 0, stream>>>(Qhi, Qlo, Khi, Klo, Vthi, Vtlo,
                                             mask, XaPk);
  // output projection
  pack_wT_kernel<<<256, 256, 0, stream>>>(Wo, WtPk);
  gemm_pk_kernel<<<512, 256, 0, stream>>>(XaPk, WtPk, bo, nullptr, nullptr, out, 0);
}

// Round 5
// 507.154 us; speedup vs baseline: 4.1042x; 1.2002x over previous
//
#include <hip/hip_runtime.h>
#include <hip/hip_bf16.h>
#include <math.h>

#define HIDDEN 1024
#define HEADS 16
#define DK 64
#define BATCH 2
#define SLEN 2048

typedef __attribute__((ext_vector_type(8))) short short8v;
typedef __attribute__((ext_vector_type(4))) float f32x4;

__device__ __forceinline__ unsigned short bf_hi(float x) {
  unsigned u = __builtin_bit_cast(unsigned, x);
  unsigned r = u + 0x7fffu + ((u >> 16) & 1u);
  return (unsigned short)(r >> 16);
}
__device__ __forceinline__ float bf_f(unsigned short h) {
  unsigned u = ((unsigned)h) << 16;
  return __builtin_bit_cast(float, u);
}
__device__ __forceinline__ unsigned pack_hl(float x) {
  unsigned short hi = bf_hi(x);
  unsigned short lo = bf_hi(x - bf_f(hi));
  return (unsigned)hi | ((unsigned)lo << 16);
}

// unpack 8 packed u32 (hi|lo per element, k ascending) into hi or lo short8v
__device__ __forceinline__ short8v unpack8(const uint4& a0, const uint4& a1,
                                           unsigned sel) {
  uint4 r;
  r.x = __builtin_amdgcn_perm(a0.y, a0.x, sel);
  r.y = __builtin_amdgcn_perm(a0.w, a0.z, sel);
  r.z = __builtin_amdgcn_perm(a1.y, a1.x, sel);
  r.w = __builtin_amdgcn_perm(a1.w, a1.z, sel);
  return __builtin_bit_cast(short8v, r);
}
#define SEL_HI 0x05040100u
#define SEL_LO 0x07060302u

#define GLB_US(p) ((const __attribute__((address_space(1))) unsigned short*)(p))
#define LDS_US(p) ((__attribute__((address_space(3))) unsigned short*)(p))

// ---------------------------------------------------------------------------
// mask [B][1][S][S] int -> bitmask u64 per (row, 64-col tile). 1MB, L2-resident.
// One wave per row, ballot per tile.
// ---------------------------------------------------------------------------
__global__ __launch_bounds__(256) void mask_bits_kernel(
    const int* __restrict__ mask, unsigned long long* __restrict__ Mb)
{
  const int row = blockIdx.x * 4 + (threadIdx.x >> 6);  // 0..B*S-1
  const int lane = threadIdx.x & 63;
  const int* mr = mask + (size_t)row * SLEN;
#pragma unroll
  for (int t = 0; t < 32; ++t) {
    int m = mr[t * 64 + lane];
    unsigned long long bits = __ballot(m != 0);
    if (lane == 0) Mb[(size_t)row * 32 + t] = bits;
  }
}

// ---------------------------------------------------------------------------
// pack fp32 -> separate bf16 hi/lo planes
// ---------------------------------------------------------------------------
__global__ __launch_bounds__(256) void pack_act_kernel(
    const float* __restrict__ src, unsigned short* __restrict__ hi,
    unsigned short* __restrict__ lo, int n4)
{
  int stride = gridDim.x * blockDim.x;
  for (int i = blockIdx.x * blockDim.x + threadIdx.x; i < n4; i += stride) {
    float4 v = ((const float4*)src)[i];
    ushort4 H, L;
    H.x = bf_hi(v.x); L.x = bf_hi(v.x - bf_f(H.x));
    H.y = bf_hi(v.y); L.y = bf_hi(v.y - bf_f(H.y));
    H.z = bf_hi(v.z); L.z = bf_hi(v.z - bf_f(H.z));
    H.w = bf_hi(v.w); L.w = bf_hi(v.w - bf_f(H.w));
    *(ushort4*)(hi + (size_t)i * 4) = H;
    *(ushort4*)(lo + (size_t)i * 4) = L;
  }
}

// ---------------------------------------------------------------------------
// pack + transpose weight: W[k][n] fp32 -> Wt hi/lo planes [n][k] bf16
// ---------------------------------------------------------------------------
__global__ __launch_bounds__(256) void pack_wT_kernel(
    const float* __restrict__ W, unsigned short* __restrict__ Whi,
    unsigned short* __restrict__ Wlo)
{
  __shared__ float T[64][65];
  const int t = threadIdx.x;
  const int bk = blockIdx.x >> 4, bn = blockIdx.x & 15;
#pragma unroll
  for (int i = 0; i < 4; ++i) {
    int k = (t >> 4) + i * 16, n = (t & 15) * 4;
    float4 v = *(const float4*)(W + (size_t)(bk * 64 + k) * HIDDEN + bn * 64 + n);
    T[k][n + 0] = v.x; T[k][n + 1] = v.y; T[k][n + 2] = v.z; T[k][n + 3] = v.w;
  }
  __syncthreads();
  const int nl = t & 63, kc = (t >> 6) * 16;
#pragma unroll
  for (int i = 0; i < 4; ++i) {
    ushort4 H, L;
    float x0 = T[kc + i * 4 + 0][nl], x1 = T[kc + i * 4 + 1][nl];
    float x2 = T[kc + i * 4 + 2][nl], x3 = T[kc + i * 4 + 3][nl];
    H.x = bf_hi(x0); L.x = bf_hi(x0 - bf_f(H.x));
    H.y = bf_hi(x1); L.y = bf_hi(x1 - bf_f(H.y));
    H.z = bf_hi(x2); L.z = bf_hi(x2 - bf_f(H.z));
    H.w = bf_hi(x3); L.w = bf_hi(x3 - bf_f(H.w));
    size_t base = (size_t)(bn * 64 + nl) * HIDDEN + bk * 64 + kc + i * 4;
    *(ushort4*)(Whi + base) = H;
    *(ushort4*)(Wlo + base) = L;
  }
}

// ---------------------------------------------------------------------------
// Split-precision bf16 MFMA GEMM, separate hi/lo planes (no unpack perms).
// C = A @ Bt^T + bias; 64x64 tile, BK=32, 4 waves (2x2 of 32x32), 1024 blocks.
// LDS: 4 planes [64][32] bf16 (4KB each, 16KB). Chunk swizzle c ^= (row>>2)&3.
// Staged via global_load_lds (linear dest, inverse-swizzled source).
// mode 0: Yf[m][n] fp32.  mode 1: Yhi/Ylo [bh][s][d].  mode 2: [bh*64+d][s].
// ---------------------------------------------------------------------------
__global__ __launch_bounds__(256) void gemm_sp_kernel(
    const unsigned short* __restrict__ Ahi, const unsigned short* __restrict__ Alo,
    const unsigned short* __restrict__ Bthi, const unsigned short* __restrict__ Btlo,
    const float* __restrict__ bias, unsigned short* __restrict__ Yhi,
    unsigned short* __restrict__ Ylo, float* __restrict__ Yf, int mode)
{
  __shared__ __align__(16) unsigned short Ah[64 * 32], Al_[64 * 32];
  __shared__ __align__(16) unsigned short Bh[64 * 32], Bl[64 * 32];

  const int tid = threadIdx.x;
  const int lb = (blockIdx.x & 7) * 128 + (blockIdx.x >> 3);  // XCD swizzle
  const int bm = lb >> 4, bn = lb & 15;
  const int m0 = bm * 64, n0 = bn * 64;
  const int w = tid >> 6, lane = tid & 63;
  const int wm = w >> 1, wn = w & 1;
  const int g = lane >> 4, qi = lane & 15;

  // staging: thread stages row tid>>2, chunk (tid&3), source col pre-swizzled
  const int tr = tid >> 2;
  const int tc = (((tid & 3) ^ ((tr >> 2) & 3)) << 3);
  const int dofs = tid * 8;  // linear LDS dest (ushort units)

  f32x4 acc[2][2];
#pragma unroll
  for (int mt = 0; mt < 2; ++mt)
#pragma unroll
    for (int nt = 0; nt < 2; ++nt) acc[mt][nt] = (f32x4){0.f, 0.f, 0.f, 0.f};

  for (int k0 = 0; k0 < HIDDEN; k0 += 32) {
    __syncthreads();
    size_t ga = (size_t)(m0 + tr) * HIDDEN + k0 + tc;
    size_t gb = (size_t)(n0 + tr) * HIDDEN + k0 + tc;
    __builtin_amdgcn_global_load_lds(GLB_US(Ahi + ga), LDS_US(Ah + dofs), 16, 0, 0);
    __builtin_amdgcn_global_load_lds(GLB_US(Alo + ga), LDS_US(Al_ + dofs), 16, 0, 0);
    __builtin_amdgcn_global_load_lds(GLB_US(Bthi + gb), LDS_US(Bh + dofs), 16, 0, 0);
    __builtin_amdgcn_global_load_lds(GLB_US(Btlo + gb), LDS_US(Bl + dofs), 16, 0, 0);
    __syncthreads();

    short8v a_h[2], a_l[2], b_h[2], b_l[2];
#pragma unroll
    for (int mt = 0; mt < 2; ++mt) {
      int R = wm * 32 + mt * 16 + qi;
      int cofs = R * 32 + ((g ^ ((R >> 2) & 3)) << 3);
      a_h[mt] = *(const short8v*)&Ah[cofs];
      a_l[mt] = *(const short8v*)&Al_[cofs];
    }
#pragma unroll
    for (int nt = 0; nt < 2; ++nt) {
      int R = wn * 32 + nt * 16 + qi;
      int cofs = R * 32 + ((g ^ ((R >> 2) & 3)) << 3);
      b_h[nt] = *(const short8v*)&Bh[cofs];
      b_l[nt] = *(const short8v*)&Bl[cofs];
    }
#pragma unroll
    for (int nt = 0; nt < 2; ++nt)
#pragma unroll
      for (int mt = 0; mt < 2; ++mt) {
        acc[mt][nt] = __builtin_amdgcn_mfma_f32_16x16x32_bf16(a_h[mt], b_h[nt], acc[mt][nt], 0, 0, 0);
        acc[mt][nt] = __builtin_amdgcn_mfma_f32_16x16x32_bf16(a_l[mt], b_h[nt], acc[mt][nt], 0, 0, 0);
        acc[mt][nt] = __builtin_amdgcn_mfma_f32_16x16x32_bf16(a_h[mt], b_l[nt], acc[mt][nt], 0, 0, 0);
      }
  }

  // epilogue
#pragma unroll
  for (int nt = 0; nt < 2; ++nt) {
    int n = n0 + wn * 32 + nt * 16 + qi;
    float bv = bias[n];
#pragma unroll
    for (int mt = 0; mt < 2; ++mt) {
#pragma unroll
      for (int r = 0; r < 4; ++r) {
        int m = m0 + wm * 32 + mt * 16 + g * 4 + r;
        float val = acc[mt][nt][r] + bv;
        if (mode == 0) {
          Yf[(size_t)m * HIDDEN + n] = val;
        } else {
          int s = m & (SLEN - 1);
          int bh_ = (m >> 11) * HEADS + (n >> 6);
          int d = n & 63;
          unsigned short hi = bf_hi(val);
          unsigned short lo = bf_hi(val - bf_f(hi));
          size_t base = (mode == 1) ? (((size_t)bh_ * SLEN + s) << 6) + d
                                    : ((size_t)(bh_ * DK + d)) * SLEN + s;
          Yhi[base] = hi;
          Ylo[base] = lo;
        }
      }
    }
  }
}

// ---------------------------------------------------------------------------
// MFMA flash attention, swapped QK^T (S^T = mfma(K,Q)) so softmax rows are
// per-lane (q = qi): 4 shuffles/tile instead of 32. Mask via u64 bitmask.
// Defer-max (THR=8) skips O-rescale on stable tiles. P stored [k][16q] u32
// (bit4^=bit7 swizzle, conflict-free) ALIASED into the K LDS region after an
// extra barrier -> LDS 32KB -> 5 blocks/CU. Staging via global_load_lds.
// ---------------------------------------------------------------------------
__global__ __launch_bounds__(256) void attn_mfma_kernel(
    const unsigned short* __restrict__ Qhi, const unsigned short* __restrict__ Qlo,
    const unsigned short* __restrict__ Khi, const unsigned short* __restrict__ Klo,
    const unsigned short* __restrict__ Vthi, const unsigned short* __restrict__ Vtlo,
    const unsigned long long* __restrict__ Mb,
    unsigned short* __restrict__ XaHi, unsigned short* __restrict__ XaLo)
{
  __shared__ __align__(16) unsigned char smem[32768];
  unsigned short* Ks_hi = (unsigned short*)smem;             // [64][64] 8KB
  unsigned short* Ks_lo = (unsigned short*)(smem + 8192);    // 8KB
  unsigned short* Vs_hi = (unsigned short*)(smem + 16384);   // 8KB
  unsigned short* Vs_lo = (unsigned short*)(smem + 24576);   // 8KB

  const int tid = threadIdx.x;
  const int bx = blockIdx.x;
  const int lb = (bx & 7) * 128 + (bx >> 3);  // XCD swizzle (1024 % 8 == 0)
  const int qt = lb & 31;
  const int bh = lb >> 5;
  const int b = bh >> 4, h = bh & 15;
  const int w = tid >> 6, lane = tid & 63;
  const int g = lane >> 4, qi = lane & 15;
  const int qbase = qt * 64 + w * 16;

  unsigned* Pw = (unsigned*)(smem + w * 4096);  // wave-private, aliases K region

  // Q fragments (same registers serve as MFMA-B operands after the swap)
  short8v qh[2], ql[2];
  {
    const unsigned short* qr_hi = Qhi + ((size_t)bh * SLEN + qbase + qi) * DK;
    const unsigned short* qr_lo = Qlo + ((size_t)bh * SLEN + qbase + qi) * DK;
    qh[0] = *(const short8v*)(qr_hi + g * 8);
    qh[1] = *(const short8v*)(qr_hi + 32 + g * 8);
    ql[0] = *(const short8v*)(qr_lo + g * 8);
    ql[1] = *(const short8v*)(qr_lo + 32 + g * 8);
  }

  f32x4 o[4];
#pragma unroll
  for (int dt = 0; dt < 4; ++dt) o[dt] = (f32x4){0.f, 0.f, 0.f, 0.f};
  float m_run = -1e30f, l_run = 0.f;

  const unsigned long long* mrow = Mb + ((size_t)b * SLEN + qbase + qi) * 32;

  for (int k0 = 0; k0 < SLEN; k0 += 64) {
    __syncthreads();
    // stage K [k][d] and V^T [d][k] (hi/lo), swizzled via pre-swizzled source
#pragma unroll
    for (int i = 0; i < 2; ++i) {
      int rloc = w * 16 + i * 8 + (lane >> 3);
      int col = ((lane & 7) * 8) ^ ((rloc & 7) << 3);
      size_t gk = ((size_t)bh * SLEN + k0 + rloc) * 64 + col;
      size_t gv = ((size_t)(bh * 64 + rloc)) * SLEN + k0 + col;
      int dofs = rloc * 64 + (lane & 7) * 8;  // linear
      __builtin_amdgcn_global_load_lds(GLB_US(Khi + gk), LDS_US(Ks_hi + dofs), 16, 0, 0);
      __builtin_amdgcn_global_load_lds(GLB_US(Klo + gk), LDS_US(Ks_lo + dofs), 16, 0, 0);
      __builtin_amdgcn_global_load_lds(GLB_US(Vthi + gv), LDS_US(Vs_hi + dofs), 16, 0, 0);
      __builtin_amdgcn_global_load_lds(GLB_US(Vtlo + gv), LDS_US(Vs_lo + dofs), 16, 0, 0);
    }
    __syncthreads();

    // QK^T swapped: S^T[k][q]; lane (g,qi) gets k = ks*16+g*4+r for q = qi
    f32x4 sf[4];
#pragma unroll
    for (int ks = 0; ks < 4; ++ks) {
      int krow = ks * 16 + qi;
      int cswz = (krow & 7) << 3;
      short8v kh0 = *(const short8v*)&Ks_hi[krow * 64 + ((g * 8) ^ cswz)];
      short8v kh1 = *(const short8v*)&Ks_hi[krow * 64 + ((32 + g * 8) ^ cswz)];
      short8v kl0 = *(const short8v*)&Ks_lo[krow * 64 + ((g * 8) ^ cswz)];
      short8v kl1 = *(const short8v*)&Ks_lo[krow * 64 + ((32 + g * 8) ^ cswz)];
      f32x4 s = {0.f, 0.f, 0.f, 0.f};
      s = __builtin_amdgcn_mfma_f32_16x16x32_bf16(kh0, qh[0], s, 0, 0, 0);
      s = __builtin_amdgcn_mfma_f32_16x16x32_bf16(kh1, qh[1], s, 0, 0, 0);
      s = __builtin_amdgcn_mfma_f32_16x16x32_bf16(kh0, ql[0], s, 0, 0, 0);
      s = __builtin_amdgcn_mfma_f32_16x16x32_bf16(kh1, ql[1], s, 0, 0, 0);
      s = __builtin_amdgcn_mfma_f32_16x16x32_bf16(kl0, qh[0], s, 0, 0, 0);
      s = __builtin_amdgcn_mfma_f32_16x16x32_bf16(kl1, qh[1], s, 0, 0, 0);
      sf[ks] = s;
    }
    __syncthreads();  // all waves done reading K region -> P may overwrite it

    // mask + per-lane softmax stats for q-row qi
    unsigned long long mw = mrow[k0 >> 6];
    unsigned s0 = ((unsigned)mw) >> (g * 4);
    unsigned s1 = ((unsigned)(mw >> 32)) >> (g * 4);
    float sv[4][4];
    float rowmax = -INFINITY;
#pragma unroll
    for (int ks = 0; ks < 4; ++ks) {
      unsigned sel = (ks < 2) ? s0 : s1;
#pragma unroll
      for (int r = 0; r < 4; ++r) {
        float x = sf[ks][r] * 0.125f;  // 1/sqrt(64)
        sv[ks][r] = ((sel >> (((ks & 1) << 4) + r)) & 1) ? x : -INFINITY;
        rowmax = fmaxf(rowmax, sv[ks][r]);
      }
    }
    rowmax = fmaxf(rowmax, __shfl_xor(rowmax, 16));
    rowmax = fmaxf(rowmax, __shfl_xor(rowmax, 32));

    if (__any(rowmax > m_run + 8.f)) {  // defer-max: rescale only on real growth
      float mnew = fmaxf(m_run, rowmax);
      float scale = __expf(m_run - mnew);
      l_run *= scale;
#pragma unroll
      for (int r = 0; r < 4; ++r) {
        float sc = __shfl(scale, g * 4 + r);  // O rows are q = g*4+r
        o[0][r] *= sc; o[1][r] *= sc; o[2][r] *= sc; o[3][r] *= sc;
      }
      m_run = mnew;
    }

    // P = exp(S - m), packed hi|lo, into [k][16] swizzled LDS
    float lsum = 0.f;
#pragma unroll
    for (int ks = 0; ks < 4; ++ks)
#pragma unroll
      for (int r = 0; r < 4; ++r) {
        float pv = __expf(sv[ks][r] - m_run);
        lsum += pv;
        int k = ks * 16 + g * 4 + r;
        int wa = (k << 4) + qi;
        wa ^= ((wa >> 7) & 1) << 4;
        Pw[wa] = pack_hl(pv);
      }
    lsum += __shfl_xor(lsum, 16);
    lsum += __shfl_xor(lsum, 32);
    l_run += lsum;

    // PV: O += Phi*Vhi + Phi*Vlo + Plo*Vhi
#pragma unroll
    for (int kh = 0; kh < 2; ++kh) {
      unsigned u0, u1, u2, u3, u4, u5, u6, u7;
      {
        int kb = kh * 32 + g * 8;
        int ra;
        ra = ((kb + 0) << 4) + qi; ra ^= ((ra >> 7) & 1) << 4; u0 = Pw[ra];
        ra = ((kb + 1) << 4) + qi; ra ^= ((ra >> 7) & 1) << 4; u1 = Pw[ra];
        ra = ((kb + 2) << 4) + qi; ra ^= ((ra >> 7) & 1) << 4; u2 = Pw[ra];
        ra = ((kb + 3) << 4) + qi; ra ^= ((ra >> 7) & 1) << 4; u3 = Pw[ra];
        ra = ((kb + 4) << 4) + qi; ra ^= ((ra >> 7) & 1) << 4; u4 = Pw[ra];
        ra = ((kb + 5) << 4) + qi; ra ^= ((ra >> 7) & 1) << 4; u5 = Pw[ra];
        ra = ((kb + 6) << 4) + qi; ra ^= ((ra >> 7) & 1) << 4; u6 = Pw[ra];
        ra = ((kb + 7) << 4) + qi; ra ^= ((ra >> 7) & 1) << 4; u7 = Pw[ra];
      }
      uint4 a0 = {u0, u1, u2, u3}, a1 = {u4, u5, u6, u7};
      short8v phi = unpack8(a0, a1, SEL_HI);
      short8v plo = unpack8(a0, a1, SEL_LO);
#pragma unroll
      for (int dt = 0; dt < 4; ++dt) {
        int drow = dt * 16 + qi;
        int vcol = (kh * 32 + g * 8) ^ ((drow & 7) << 3);
        short8v vh = *(const short8v*)&Vs_hi[drow * 64 + vcol];
        short8v vl = *(const short8v*)&Vs_lo[drow * 64 + vcol];
        o[dt] = __builtin_amdgcn_mfma_f32_16x16x32_bf16(phi, vh, o[dt], 0, 0, 0);
        o[dt] = __builtin_amdgcn_mfma_f32_16x16x32_bf16(phi, vl, o[dt], 0, 0, 0);
        o[dt] = __builtin_amdgcn_mfma_f32_16x16x32_bf16(plo, vh, o[dt], 0, 0, 0);
      }
    }
  }

  // normalize + write Xa hi/lo planes [b*S+s][h*64+d]
#pragma unroll
  for (int r = 0; r < 4; ++r) {
    float lr = __shfl(l_run, g * 4 + r);  // l for q-row g*4+r lives at lane qi=g*4+r
    float inv = lr > 0.f ? 1.f / lr : 0.f;
    size_t rowa = ((size_t)(b * SLEN) + qbase + g * 4 + r) * HIDDEN + h * DK;
#pragma unroll
    for (int dt = 0; dt < 4; ++dt) {
      float val = o[dt][r] * inv;
      unsigned short hi = bf_hi(val);
      XaHi[rowa + dt * 16 + qi] = hi;
      XaLo[rowa + dt * 16 + qi] = bf_hi(val - bf_f(hi));
    }
  }
}

// ---------------------------------------------------------------------------
extern "C" void kernel_launch(void* const* d_in, const int* in_sizes, int n_in,
                              void* d_out, int out_size, void* d_ws, size_t ws_size,
                              hipStream_t stream) {
  const float* q   = (const float*)d_in[0];
  const float* k   = (const float*)d_in[1];
  const float* v   = (const float*)d_in[2];
  const int*  mask = (const int*)d_in[3];
  const float* Wq  = (const float*)d_in[4];
  const float* bq  = (const float*)d_in[5];
  const float* Wk  = (const float*)d_in[6];
  const float* bk  = (const float*)d_in[7];
  const float* Wv  = (const float*)d_in[8];
  const float* bv  = (const float*)d_in[9];
  const float* Wo  = (const float*)d_in[10];
  const float* bo  = (const float*)d_in[11];
  float* out = (float*)d_out;

  const size_t HSZ = (size_t)BATCH * SLEN * HIDDEN;   // 4,194,304 elems
  const size_t WSZ = (size_t)HIDDEN * HIDDEN;         // 1,048,576 elems
  unsigned short* wsu = (unsigned short*)d_ws;
  unsigned short* Qhi = wsu;
  unsigned short* Qlo = wsu + HSZ;
  unsigned short* Khi = wsu + 2 * HSZ;
  unsigned short* Klo = wsu + 3 * HSZ;
  unsigned short* Vthi = wsu + 4 * HSZ;
  unsigned short* Vtlo = wsu + 5 * HSZ;
  unsigned short* Ahi_ = wsu + 6 * HSZ;   // also XaHi (attention output plane)
  unsigned short* Alo_ = wsu + 7 * HSZ;   // also XaLo
  unsigned short* Wthi = wsu + 8 * HSZ;
  unsigned short* Wtlo = wsu + 8 * HSZ + WSZ;
  unsigned long long* Mb = (unsigned long long*)(wsu + 8 * HSZ + 2 * WSZ);

  const int n4 = (int)(HSZ / 4);

  mask_bits_kernel<<<BATCH * SLEN / 4, 256, 0, stream>>>(mask, Mb);

  // Q projection
  pack_act_kernel<<<1024, 256, 0, stream>>>(q, Ahi_, Alo_, n4);
  pack_wT_kernel<<<256, 256, 0, stream>>>(Wq, Wthi, Wtlo);
  gemm_sp_kernel<<<1024, 256, 0, stream>>>(Ahi_, Alo_, Wthi, Wtlo, bq, Qhi, Qlo, nullptr, 1);
  // K projection
  pack_act_kernel<<<1024, 256, 0, stream>>>(k, Ahi_, Alo_, n4);
  pack_wT_kernel<<<256, 256, 0, stream>>>(Wk, Wthi, Wtlo);
  gemm_sp_kernel<<<1024, 256, 0, stream>>>(Ahi_, Alo_, Wthi, Wtlo, bk, Khi, Klo, nullptr, 1);
  // V projection (transposed output)
  pack_act_kernel<<<1024, 256, 0, stream>>>(v, Ahi_, Alo_, n4);
  pack_wT_kernel<<<256, 256, 0, stream>>>(Wv, Wthi, Wtlo);
  gemm_sp_kernel<<<1024, 256, 0, stream>>>(Ahi_, Alo_, Wthi, Wtlo, bv, Vthi, Vtlo, nullptr, 2);

  // attention -> Xa planes (reuse A-plane buffers)
  attn_mfma_kernel<<<1024, 256, 0, stream>>>(Qhi, Qlo, Khi, Klo, Vthi, Vtlo,
                                             Mb, Ahi_, Alo_);

  // output projection
  pack_wT_kernel<<<256, 256, 0, stream>>>(Wo, Wthi, Wtlo);
  gemm_sp_kernel<<<1024, 256, 0, stream>>>(Ahi_, Alo_, Wthi, Wtlo, bo, nullptr, nullptr, out, 0);
}